// Round 6
// baseline (246.373 us; speedup 1.0000x reference)
//
#include <hip/hip_runtime.h>

#define NPAR 8
#define LPAR 16
#define OCH 128
#define HH 256
#define WW 256
#define HWSZ (HH*WW)

typedef _Float16 f16x8 __attribute__((ext_vector_type(8)));
typedef _Float16 f16x4 __attribute__((ext_vector_type(4)));
typedef _Float16 f16x2 __attribute__((ext_vector_type(2)));
typedef float    f32x4 __attribute__((ext_vector_type(4)));

// LDS (halves), unioned:
//   conv phase : xs = [6 dyr][20 wp][64 col], col = nc*16+ci, XOR-swizzled
//                (7680 halves = 15360 B)
//   epilogue   : votes = [128 rows][132], col = lp*8+np  (16896 halves = 33792 B)
#define SMEM_HALVES 16896
#define VROW 132

__device__ __forceinline__ int xs_addr(int dyr, int wp, int col) {
    return (dyr * 20 + wp) * 64 + (col ^ ((wp & 7) << 3));
}

// sum over each aligned quad of lanes via DPP quad_perm (pure VALU, no DS pipe)
__device__ __forceinline__ float quad_sum4(float v) {
    int t = __builtin_amdgcn_update_dpp(0, __float_as_int(v), 0xB1, 0xF, 0xF, true); // [1,0,3,2]
    v += __int_as_float(t);
    t = __builtin_amdgcn_update_dpp(0, __float_as_int(v), 0x4E, 0xF, 0xF, true);     // [2,3,0,1]
    v += __int_as_float(t);
    return v;
}

// Pre-pass: W (f32 [128 oc][16 ci][25 tap]) -> ws fp16 [13 kk][128 oc][32 q]
// q = p*8+j with tap = 2kk+(p>>1), ci = (p&1)*8 + j  (exact B-fragment order).
__global__ void reorder_W_kernel(const float* __restrict__ Wg,
                                 _Float16* __restrict__ ws) {
    int idx = blockIdx.x * 256 + threadIdx.x;
    if (idx >= 13 * 128 * 32) return;
    const int q  = idx & 31;
    const int oc = (idx >> 5) & 127;
    const int kk = idx >> 12;
    const int tap = 2 * kk + (q >> 4);
    const int ci  = ((q >> 3) & 1) * 8 + (q & 7);
    const float v = (tap < 25) ? Wg[oc * 400 + ci * 25 + tap] : 0.f;
    ws[idx] = (_Float16)v;
}

// Block = 2 rows x 16 px. 4 waves: wave w -> row rw=w>>1, oc-half oh=w&1.
// acc[4][4] = 64 acc regs -> target 3 waves/SIMD (512-reg pool / ~170).
__global__ __launch_bounds__(256, 3)
void capsule_mfma5_kernel(const float* __restrict__ x,
                          const _Float16* __restrict__ wsf,
                          float* __restrict__ out) {
    __shared__ _Float16 sm[SMEM_HALVES];

    const int tid = threadIdx.x;
    const int w   = tid >> 6;          // wave 0..3
    const int l   = tid & 63;

    // XCD-aware swizzle: 8192 wgs / 8 XCDs = 1024 contiguous tiles per XCD.
    const int blk   = ((blockIdx.x & 7) << 10) + (blockIdx.x >> 3);
    const int b     = blk >> 11;
    const int rt    = blk & 2047;
    const int hrow0 = (rt >> 4) << 1;  // 128 row-pair tiles
    const int w0    = (rt & 15) << 4;  // 16 col-tiles of 16 px

    // ---- stage x tile [6 dyr][20 wp][64 ch] as fp16, b32 ci-pair writes ----
    for (int i = 0; i < 15; ++i) {
        const unsigned idx = i * 256 + tid;          // 0..3839
        const unsigned q   = idx / 20u;              // magic-mul (const divisor)
        const int wp  = idx - q * 20u;
        const int cip = q & 7;
        const int t2  = q >> 3;                      // 0..23
        const int nc  = t2 & 3;
        const int dyr = t2 >> 2;                     // 0..5
        const int hh  = hrow0 + dyr - 2;
        const int wg  = w0 + wp - 2;
        const bool ok = (hh >= 0) && (hh < HH) && (wg >= 0) && (wg < WW);
        const float* src = x + (((size_t)(b * 4 + nc) * 16 + cip * 2) * HH + hh) * (size_t)WW + wg;
        const float v0 = ok ? src[0] : 0.f;
        const float v1 = ok ? src[HWSZ] : 0.f;
        *(f16x2*)&sm[xs_addr(dyr, wp, nc * 16 + cip * 2)] =
            (f16x2){(_Float16)v0, (_Float16)v1};
    }
    __syncthreads();

    // ---- MFMA conv: per wave M=64 (16px x 4nc), N=64 (oc half), K=416 ----
    const int rwc = w >> 1;            // wave's row (0/1)
    const int oh  = w & 1;             // wave's oc-half
    const int p   = l >> 4;
    const int ml  = l & 15;
    const int ciA = (p & 1) * 8;
    const int pxA = ml >> 2;
    const int ncA = ml & 3;
    const int bfbase = (oh * 64 + ml) * 32 + p * 8;

    f32x4 acc[4][4];
#pragma unroll
    for (int a = 0; a < 4; ++a)
#pragma unroll
        for (int bb = 0; bb < 4; ++bb)
            acc[a][bb] = (f32x4){0.f, 0.f, 0.f, 0.f};

#pragma unroll
    for (int kk = 0; kk < 13; ++kk) {
        f16x8 bf[4];
#pragma unroll
        for (int bb = 0; bb < 4; ++bb)
            bf[bb] = *(const f16x8*)&wsf[kk * 4096 + bb * 512 + bfbase];

        int tap = 2 * kk + (p >> 1);
        if (tap > 24) tap = 24;        // pad taps: B side is zero
        const int dy = tap / 5;
        const int dx = tap - 5 * dy;

        f16x8 af[4];
#pragma unroll
        for (int a = 0; a < 4; ++a)
            af[a] = *(const f16x8*)&sm[xs_addr(rwc + dy, a * 4 + pxA + dx, ncA * 16 + ciA)];

#pragma unroll
        for (int a = 0; a < 4; ++a)
#pragma unroll
            for (int bb = 0; bb < 4; ++bb)
                acc[a][bb] = __builtin_amdgcn_mfma_f32_16x16x32_f16(
                    af[a], bf[bb], acc[a][bb], 0, 0, 0);
    }
    __syncthreads();   // xs region about to be overwritten by votes

    // ---- epilogue: acc -> votes LDS fp16 (col' = lp*8 + np, np = oh*4+bb) ----
    // C layout: M-row = a*16 + p*4 + reg -> (px = a*4+p, nc = reg); oc col = bb*16+ml
#pragma unroll
    for (int a = 0; a < 4; ++a) {
#pragma unroll
        for (int reg = 0; reg < 4; ++reg) {
            f16x4 pk;
#pragma unroll
            for (int bb = 0; bb < 4; ++bb) pk[bb] = (_Float16)acc[a][bb][reg];
            const int R = rwc * 64 + a * 16 + p * 4 + reg;
            *(f16x4*)&sm[R * VROW + ml * 8 + oh * 4] = pk;
        }
    }
    __syncthreads();

    // ---- routing: thread = (rw, px, h, nc); 2 threads/row split lp halves ----
    const int ncR = tid & 3;           // bits 0-1: DPP quad = nc-sum
    const int h   = (tid >> 2) & 1;    // bit 2: lp-half, exchange via shfl_xor 4
    const int pxx = (tid >> 3) & 15;
    const int rw  = tid >> 7;

    const int R = rw * 64 + pxx * 4 + ncR;
    f16x8 vh[8];                       // votes, lp in [h*8, h*8+8), packed np
#pragma unroll
    for (int c8 = 0; c8 < 8; ++c8)
        vh[c8] = *(const f16x8*)&sm[R * VROW + (h * 8 + c8) * 8];

    float* outb = out + (size_t)b * OCH * HWSZ
                + (size_t)(hrow0 + rw) * WW + (w0 + pxx);

    float sims[NPAR];
#pragma unroll
    for (int i = 0; i < NPAR; ++i) sims[i] = 0.f;

#pragma unroll
    for (int it = 0; it < 3; ++it) {
        float mx = sims[0];
#pragma unroll
        for (int i = 1; i < NPAR; ++i) mx = fmaxf(mx, sims[i]);
        float e[NPAR];
        float se = 0.f;
#pragma unroll
        for (int i = 0; i < NPAR; ++i) { e[i] = __expf(sims[i] - mx); se += e[i]; }
        const float inv = 1.f / se;

#pragma unroll
        for (int np_ = 0; np_ < NPAR; ++np_) {
            const float c = e[np_] * inv;
            float n2 = 0.f, dot = 0.f;
            float keep[4] = {0.f, 0.f, 0.f, 0.f};   // static-indexed only
#pragma unroll
            for (int c8 = 0; c8 < 8; ++c8) {
                const float vv = (float)vh[c8][np_];
                const float t  = quad_sum4(c * vv);      // pb[lp] via DPP nc-sum
                n2  = fmaf(t, t, n2);
                dot = fmaf(vv, t, dot);
                if (it == 2 && (c8 >> 2) == (ncR & 1))   // cndmask, last it only
                    keep[c8 & 3] = t;
            }
            // combine the two lp-halves
            n2  += __shfl_xor(n2, 4);
            dot += __shfl_xor(dot, 4);
            const float scale = sqrtf(n2) / (1.f + n2 + 1e-4f);
            sims[np_] += scale * dot;

            if (it == 2 && (ncR >> 1) == h) {
                // this thread owns lp = ncR*4+j  (j = 0..3)
#pragma unroll
                for (int j = 0; j < 4; ++j)
                    outb[(size_t)(np_ * LPAR + ncR * 4 + j) * HWSZ] = scale * keep[j];
            }
        }
    }
}

extern "C" void kernel_launch(void* const* d_in, const int* in_sizes, int n_in,
                              void* d_out, int out_size, void* d_ws, size_t ws_size,
                              hipStream_t stream) {
    const float* x  = (const float*)d_in[0];   // (4,4,16,256,256) f32
    const float* Wg = (const float*)d_in[1];   // (128,16,5,5) f32
    float* out = (float*)d_out;                // (4,8,16,256,256) f32
    _Float16* ws = (_Float16*)d_ws;            // 13*128*32 halves = 106496 B
    (void)in_sizes; (void)n_in; (void)ws_size; (void)out_size;

    hipLaunchKernelGGL(reorder_W_kernel, dim3(208), dim3(256), 0, stream, Wg, ws);
    hipLaunchKernelGGL(capsule_mfma5_kernel, dim3(8192), dim3(256), 0, stream,
                       x, ws, out);
}

// Round 8
// 244.170 us; speedup vs baseline: 1.0090x; 1.0090x over previous
//
#include <hip/hip_runtime.h>

#define NPAR 8
#define LPAR 16
#define OCH 128
#define HH 256
#define WW 256
#define HWSZ (HH*WW)

typedef _Float16 f16x8 __attribute__((ext_vector_type(8)));
typedef _Float16 f16x4 __attribute__((ext_vector_type(4)));
typedef _Float16 f16x2 __attribute__((ext_vector_type(2)));
typedef float    f32x4 __attribute__((ext_vector_type(4)));

// LDS (halves), unioned:
//   conv phase : xs = [6 dyr][20 wp][64 col], col = nc*16+ci, XOR-swizzled
//                (7680 halves = 15360 B)
//   epilogue   : votes = [128 rows][132], col = lp*8+np  (16896 halves = 33792 B)
#define SMEM_HALVES 16896
#define VROW 132

__device__ __forceinline__ int xs_addr(int dyr, int wp, int col) {
    return (dyr * 20 + wp) * 64 + (col ^ ((wp & 7) << 3));
}

#if defined(__has_builtin)
#if __has_builtin(__builtin_amdgcn_fdot2)
#define HAVE_FDOT2 1
#endif
#endif

__device__ __forceinline__ float fdot2_acc(f16x2 a, f16x2 b, float c) {
#ifdef HAVE_FDOT2
    return __builtin_amdgcn_fdot2(a, b, c, false);   // v_dot2_f32_f16
#else
    return c + (float)a[0] * (float)b[0] + (float)a[1] * (float)b[1];
#endif
}

// packed quad-sum: DPP quad_perm works on the b32 container -> both f16 halves
__device__ __forceinline__ f16x2 quad_sum4_pk(f16x2 v) {
    int t = __builtin_amdgcn_update_dpp(0, __builtin_bit_cast(int, v),
                                        0xB1, 0xF, 0xF, true);   // [1,0,3,2]
    v = v + __builtin_bit_cast(f16x2, t);                        // v_pk_add_f16
    t = __builtin_amdgcn_update_dpp(0, __builtin_bit_cast(int, v),
                                    0x4E, 0xF, 0xF, true);       // [2,3,0,1]
    v = v + __builtin_bit_cast(f16x2, t);
    return v;
}

// Pre-pass: W (f32 [128 oc][16 ci][25 tap]) -> ws fp16 [13 kk][128 oc][32 q]
// q = p*8+j with tap = 2kk+(p>>1), ci = (p&1)*8 + j  (exact B-fragment order).
__global__ void reorder_W_kernel(const float* __restrict__ Wg,
                                 _Float16* __restrict__ ws) {
    int idx = blockIdx.x * 256 + threadIdx.x;
    if (idx >= 13 * 128 * 32) return;
    const int q  = idx & 31;
    const int oc = (idx >> 5) & 127;
    const int kk = idx >> 12;
    const int tap = 2 * kk + (q >> 4);
    const int ci  = ((q >> 3) & 1) * 8 + (q & 7);
    const float v = (tap < 25) ? Wg[oc * 400 + ci * 25 + tap] : 0.f;
    ws[idx] = (_Float16)v;
}

// Block = 2 rows x 16 px. 4 waves: wave w -> row rw=w>>1, oc-half oh=w&1.
__global__ __launch_bounds__(256, 3)
void capsule_mfma6_kernel(const float* __restrict__ x,
                          const _Float16* __restrict__ wsf,
                          float* __restrict__ out) {
    __shared__ _Float16 sm[SMEM_HALVES];

    const int tid = threadIdx.x;
    const int w   = tid >> 6;          // wave 0..3
    const int l   = tid & 63;

    // XCD-aware swizzle: 8192 wgs / 8 XCDs = 1024 contiguous tiles per XCD.
    const int blk   = ((blockIdx.x & 7) << 10) + (blockIdx.x >> 3);
    const int b     = blk >> 11;
    const int rt    = blk & 2047;
    const int hrow0 = (rt >> 4) << 1;  // 128 row-pair tiles
    const int w0    = (rt & 15) << 4;  // 16 col-tiles of 16 px

    // ---- stage x tile [6 dyr][20 wp][64 ch] as fp16, b32 ci-pair writes ----
    for (int i = 0; i < 15; ++i) {
        const unsigned idx = i * 256 + tid;          // 0..3839
        const unsigned q   = idx / 20u;              // magic-mul (const divisor)
        const int wp  = idx - q * 20u;
        const int cip = q & 7;
        const int t2  = q >> 3;                      // 0..23
        const int nc  = t2 & 3;
        const int dyr = t2 >> 2;                     // 0..5
        const int hh  = hrow0 + dyr - 2;
        const int wg  = w0 + wp - 2;
        const bool ok = (hh >= 0) && (hh < HH) && (wg >= 0) && (wg < WW);
        const float* src = x + (((size_t)(b * 4 + nc) * 16 + cip * 2) * HH + hh) * (size_t)WW + wg;
        const float v0 = ok ? src[0] : 0.f;
        const float v1 = ok ? src[HWSZ] : 0.f;
        *(f16x2*)&sm[xs_addr(dyr, wp, nc * 16 + cip * 2)] =
            (f16x2){(_Float16)v0, (_Float16)v1};
    }
    __syncthreads();

    // ---- MFMA conv: per wave M=64 (16px x 4nc), N=64 (oc half), K=416 ----
    const int rwc = w >> 1;            // wave's row (0/1)
    const int oh  = w & 1;             // wave's oc-half
    const int p   = l >> 4;
    const int ml  = l & 15;
    const bool hiT = (p & 2) != 0;     // tap parity select (p>>1)
    const int ciA = (p & 1) * 8;
    const int pxA = ml >> 2;
    const int ncA = ml & 3;
    const int bfbase = (oh * 64 + ml) * 32 + p * 8;

    f32x4 acc[4][4];
#pragma unroll
    for (int a = 0; a < 4; ++a)
#pragma unroll
        for (int bb = 0; bb < 4; ++bb)
            acc[a][bb] = (f32x4){0.f, 0.f, 0.f, 0.f};

#pragma unroll
    for (int kk = 0; kk < 13; ++kk) {
        f16x8 bf[4];
#pragma unroll
        for (int bb = 0; bb < 4; ++bb)
            bf[bb] = *(const f16x8*)&wsf[kk * 4096 + bb * 512 + bfbase];

        // compile-time dy/dx pairs, one cndmask each (kills runtime /5, %5)
        const int t0 = 2 * kk;
        const int t1 = (2 * kk + 1 > 24) ? 24 : 2 * kk + 1;
        const int dy = hiT ? (t1 / 5) : (t0 / 5);
        const int dx = hiT ? (t1 % 5) : (t0 % 5);

        f16x8 af[4];
#pragma unroll
        for (int a = 0; a < 4; ++a)
            af[a] = *(const f16x8*)&sm[xs_addr(rwc + dy, a * 4 + pxA + dx, ncA * 16 + ciA)];

#pragma unroll
        for (int a = 0; a < 4; ++a)
#pragma unroll
            for (int bb = 0; bb < 4; ++bb)
                acc[a][bb] = __builtin_amdgcn_mfma_f32_16x16x32_f16(
                    af[a], bf[bb], acc[a][bb], 0, 0, 0);
    }
    __syncthreads();   // xs region about to be overwritten by votes

    // ---- epilogue: acc -> votes LDS fp16 (col = lp*8 + np, np = oh*4+bb) ----
    // C layout: M-row = a*16 + p*4 + reg -> (px = a*4+p, nc = reg); oc col = bb*16+ml
#pragma unroll
    for (int a = 0; a < 4; ++a) {
#pragma unroll
        for (int reg = 0; reg < 4; ++reg) {
            f16x4 pk;
#pragma unroll
            for (int bb = 0; bb < 4; ++bb) pk[bb] = (_Float16)acc[a][bb][reg];
            const int R = rwc * 64 + a * 16 + p * 4 + reg;
            *(f16x4*)&sm[R * VROW + ml * 8 + oh * 4] = pk;
        }
    }
    __syncthreads();

    // ---- routing: thread = (rw, px, h, nc); 2 threads/row split lp halves ----
    const int ncR = tid & 3;           // bits 0-1: DPP quad = nc-sum
    const int h   = (tid >> 2) & 1;    // bit 2: lp-half, exchange via shfl_xor 4
    const int pxx = (tid >> 3) & 15;
    const int rw  = tid >> 7;

    const int R = rw * 64 + pxx * 4 + ncR;
    f16x8 vh[8];                       // votes, lp in [h*8, h*8+8), packed np
#pragma unroll
    for (int c8 = 0; c8 < 8; ++c8)
        vh[c8] = *(const f16x8*)&sm[R * VROW + (h * 8 + c8) * 8];

    float* outb = out + (size_t)b * OCH * HWSZ
                + (size_t)(hrow0 + rw) * WW + (w0 + pxx);

    float sims[NPAR];
#pragma unroll
    for (int i = 0; i < NPAR; ++i) sims[i] = 0.f;

#pragma unroll
    for (int it = 0; it < 3; ++it) {
        float mx = fmaxf(fmaxf(fmaxf(sims[0], sims[1]), fmaxf(sims[2], sims[3])),
                         fmaxf(fmaxf(sims[4], sims[5]), fmaxf(sims[6], sims[7])));
        float e[NPAR];
        float se = 0.f;
#pragma unroll
        for (int i = 0; i < NPAR; ++i) { e[i] = __expf(sims[i] - mx); se += e[i]; }
        const float inv = 1.f / se;

#pragma unroll
        for (int np_ = 0; np_ < NPAR; ++np_) {
            const float cf = e[np_] * inv;
            const f16x2 cp = (f16x2){(_Float16)cf, (_Float16)cf};
            float n2 = 0.f, dot = 0.f;
            f16x2 keep0 = (f16x2){(_Float16)0.f, (_Float16)0.f};
            f16x2 keep1 = keep0;
#pragma unroll
            for (int k = 0; k < 4; ++k) {           // lp-pairs 2k,2k+1 (within half)
                const f16x2 vv = (f16x2){vh[2 * k][np_], vh[2 * k + 1][np_]};
                const f16x2 t2 = quad_sum4_pk(cp * vv);     // pb pair via DPP nc-sum
                n2  = fdot2_acc(t2, t2, n2);                // f32 accumulation
                dot = fdot2_acc(vv, t2, dot);
                if (it == 2 && (k >> 1) == (ncR & 1)) {     // cndmask, last it only
                    if (k & 1) keep1 = t2; else keep0 = t2;
                }
            }
            // combine the two lp-halves
            n2  += __shfl_xor(n2, 4);
            dot += __shfl_xor(dot, 4);
            const float scale = sqrtf(n2) / (1.f + n2 + 1e-4f);
            sims[np_] += scale * dot;

            if (it == 2 && (ncR >> 1) == h) {
                // this thread owns lp = ncR*4+j (j=0..3): pairs keep0/keep1
                outb[(size_t)(np_ * LPAR + ncR * 4 + 0) * HWSZ] = scale * (float)keep0[0];
                outb[(size_t)(np_ * LPAR + ncR * 4 + 1) * HWSZ] = scale * (float)keep0[1];
                outb[(size_t)(np_ * LPAR + ncR * 4 + 2) * HWSZ] = scale * (float)keep1[0];
                outb[(size_t)(np_ * LPAR + ncR * 4 + 3) * HWSZ] = scale * (float)keep1[1];
            }
        }
    }
}

extern "C" void kernel_launch(void* const* d_in, const int* in_sizes, int n_in,
                              void* d_out, int out_size, void* d_ws, size_t ws_size,
                              hipStream_t stream) {
    const float* x  = (const float*)d_in[0];   // (4,4,16,256,256) f32
    const float* Wg = (const float*)d_in[1];   // (128,16,5,5) f32
    float* out = (float*)d_out;                // (4,8,16,256,256) f32
    _Float16* ws = (_Float16*)d_ws;            // 13*128*32 halves = 106496 B
    (void)in_sizes; (void)n_in; (void)ws_size; (void)out_size;

    hipLaunchKernelGGL(reorder_W_kernel, dim3(208), dim3(256), 0, stream, Wg, ws);
    hipLaunchKernelGGL(capsule_mfma6_kernel, dim3(8192), dim3(256), 0, stream,
                       x, ws, out);
}